// Round 8
// baseline (861.468 us; speedup 1.0000x reference)
//
#include <hip/hip_runtime.h>

// Pipeline: conv3x3(64->128)+ReLU -> conv3x3(128->32)+ReLU -> bilinear x2 -> conv3x3(32->1)
// N=48, H=W=128 input, out [48,1,256,256] fp32.
//
// Round 12: conv1 staging -> global_load_lds (width=16) with both-sides XOR swizzle.
//  R11: conv1 198us, FETCH 67MB / WRITE 199MB (~ideal), MfmaUtil 25%, conflicts 0 ->
//  structure-bound. The reg-staged path {11 loads, vmcnt drain, 11 ds_writes, lgkm
//  drain, barrier} is replaced by 11 global_load_lds issues + barrier (no VGPR
//  round-trip; guide's m93->m97 lever). Since gload_lds writes linearly, the pitch-72
//  pad is replaced by chunk-XOR swizzle: LDS[p*128B + m*16B] holds logical chunk
//  m^(p&7) (pre-swizzled per-lane GLOBAL src addr), reads XOR the same way ->
//  8 consecutive lanes tile all 32 banks (conflict-free, same property as pitch 72).
//  xh gets a 1-px zero border [48][132][130][64] (+zero_border kernel) so staging has
//  NO guards; tail lanes read harmless junk into unused LDS slots.
//  conv2 (R11 split-plane, left top-5) / conv3 / repack_w unchanged.
// Workspace: [A: xh 101MB bordered][B: y1h 192MB split-plane][C: y2h 48MB][W].

typedef _Float16 half_t;
typedef _Float16 half2_t __attribute__((ext_vector_type(2)));
typedef _Float16 half4_t __attribute__((ext_vector_type(4)));
typedef _Float16 half8   __attribute__((ext_vector_type(8)));
typedef float    floatx4  __attribute__((ext_vector_type(4)));
typedef float    floatx16 __attribute__((ext_vector_type(16)));

typedef const __attribute__((address_space(1))) char* gptr_t;
typedef __attribute__((address_space(3))) char* lptr_t;

// ---------- pre-pass: weights fp32 [co][ci][3][3] -> fp16 [tap][co][ci] ----------
__global__ __launch_bounds__(256) void repack_w(
    const float* __restrict__ W1, const float* __restrict__ W2,
    const float* __restrict__ W3, half_t* __restrict__ wh1,
    half_t* __restrict__ wh2, half_t* __restrict__ wh3)
{
    int idx = blockIdx.x * 256 + threadIdx.x;
    if (idx < 73728) {                       // wh1[tap][128][64]
        int ci = idx & 63, co = (idx >> 6) & 127, tap = idx >> 13;
        wh1[idx] = (half_t)W1[(co * 64 + ci) * 9 + tap];
    } else if (idx < 110592) {               // wh2[tap][32][128]
        int j = idx - 73728;
        int ci = j & 127, co = (j >> 7) & 31, tap = j >> 12;
        wh2[j] = (half_t)W2[(co * 128 + ci) * 9 + tap];
    } else if (idx < 110880) {               // wh3[tap][32]
        int j = idx - 110592;
        int ci = j & 31, tap = j >> 5;
        wh3[j] = (half_t)W3[ci * 9 + tap];
    }
}

// ---------- zero the 1-px border of bordered xh [48][132][130][64] ----------
__global__ __launch_bounds__(256) void zero_border(half_t* __restrict__ xh)
{
    const int n = blockIdx.x;
    half_t* base = xh + (size_t)n * (132 * 130 * 64);
    for (int i = threadIdx.x; i < 516; i += 256) {
        int gy, gx;
        if (i < 130)      { gy = 0;   gx = i; }
        else if (i < 260) { gy = 129; gx = i - 130; }
        else if (i < 388) { gy = i - 260 + 1; gx = 0; }
        else              { gy = i - 388 + 1; gx = 129; }
        half8 z = {};
        half_t* p = base + ((size_t)gy * 130 + gx) * 64;
#pragma unroll
        for (int k = 0; k < 8; ++k)
            *(half8*)(p + k * 8) = z;
    }
}

// ---------- pre-pass: x fp32 NCHW -> xh fp16 bordered-NHWC [48][132][130][64] ----------
__global__ __launch_bounds__(256) void repack_x(
    const float* __restrict__ x, half_t* __restrict__ xh)
{
    const int tid = threadIdx.x;
    const int px = tid & 127, rr = tid >> 7;
    const int y = blockIdx.x * 2 + rr;
    const int n = blockIdx.y;
    const float* xn = x + (size_t)n * 64 * 16384 + (size_t)y * 128 + px;
    half2_t hb[32];
#pragma unroll
    for (int c2 = 0; c2 < 32; ++c2) {
        float f0 = xn[(size_t)(2 * c2) * 16384];
        float f1 = xn[(size_t)(2 * c2 + 1) * 16384];
        half2_t h; h.x = (half_t)f0; h.y = (half_t)f1;
        hb[c2] = h;
    }
    half_t* op = xh + (((size_t)n * 132 + (y + 1)) * 130 + (px + 1)) * 64;
#pragma unroll
    for (int k = 0; k < 8; ++k)
        *(half8*)(op + k * 8) = *(half8*)(&hb[k * 4]);
}

// ---------- conv1: 64->128, relu, 32x32x16 MFMA ----------
// grid (4, 16, 48). block = 128co x (32w x 8h). 4 waves = (wco 0..1) x (wpx 0..1).
// wave = 64co x (32w x 4h) -> acc[2][4] floatx16 (128 AGPR), 8 MFMA per 6 loads.
// Stage: 11x global_load_lds dwordx4, linear LDS [352 px][64 ch], chunk-XOR swizzle
// m^(p&7) applied on per-lane global src AND on ds_read addr (conflict-free both ways).
__global__ __launch_bounds__(256, 2) void conv1_mfma(
    const half_t* __restrict__ xh,   // [n][132][130][64] bordered
    const half_t* __restrict__ wh,   // [9][128][64]
    const float*  __restrict__ bias, // [128]
    half_t* __restrict__ y1h)        // [n][4][128][128][32]
{
    __shared__ half_t lx[352 * 64];       // 45056 B, linear [pixel][64ch]
    const int tid  = threadIdx.x;
    const int lane = tid & 63;
    const int wave = tid >> 6;
    const int l31 = lane & 31, lq = lane >> 5;
    const int wco = wave >> 1, wpx = wave & 1;
    const int x0 = blockIdx.x * 32, y0 = blockIdx.y * 8;
    const int n = blockIdx.z;
    const half_t* xn = xh + (size_t)n * (132 * 130 * 64);

    // stage: tile pixels p = row*34+col, row 0..9 (bordered gy=y0+row), col 0..33.
    // 2816 chunks issued (>=2720 used); tail reads valid junk into unused slots.
#pragma unroll
    for (int k = 0; k < 11; ++k) {
        int idx = tid + k * 256;          // chunk index; wave-contig groups of 64
        int m = idx & 7, p = idx >> 3;
        int row = p / 34, col = p - row * 34;
        int sw = m ^ (p & 7);             // logical chunk living in slot m of pixel p
        const half_t* src = xn + ((size_t)(y0 + row) * 130 + (x0 + col)) * 64 + sw * 8;
        half_t* dst = &lx[(size_t)(k * 256 + wave * 64) * 8];   // wave-uniform base
        __builtin_amdgcn_global_load_lds((gptr_t)src, (lptr_t)dst, 16, 0, 0);
    }
    __syncthreads();   // compiler drains vmcnt before s_barrier

    floatx16 acc[2][4] = {};

#pragma unroll
    for (int tap = 0; tap < 9; ++tap) {
        const int dy = tap / 3, dx = tap % 3;   // compile-time under unroll
        // A: lane holds W[co = wco*64 + mf*32 + l31][k = kc*16 + lq*8 + j]
        const half_t* wt = wh + tap * (128 * 64) + (wco * 64 + l31) * 64 + lq * 8;
        const int pr0 = (wpx * 4 + dy) * 34 + l31 + dx;   // nf=0 pixel index
#pragma unroll
        for (int kc = 0; kc < 4; ++kc) {
            half8 a0 = *(const half8*)(wt + kc * 16);
            half8 a1 = *(const half8*)(wt + 32 * 64 + kc * 16);
            half8 b[4];
#pragma unroll
            for (int nf = 0; nf < 4; ++nf) {
                int p = pr0 + nf * 34;
                int m = (kc * 2 + lq) ^ (p & 7);
                b[nf] = *(const half8*)(&lx[p * 64 + m * 8]);
            }
#pragma unroll
            for (int nf = 0; nf < 4; ++nf) {
                acc[0][nf] = __builtin_amdgcn_mfma_f32_32x32x16_f16(a0, b[nf], acc[0][nf], 0, 0, 0);
                acc[1][nf] = __builtin_amdgcn_mfma_f32_32x32x16_f16(a1, b[nf], acc[1][nf], 0, 0, 0);
            }
        }
    }

    // C/D 32x32: col(px) = l31, row(co local) = (reg&3) + 8*(reg>>2) + 4*lq
    // store to channel-quarter plane q = wco*2 + mf, local channel lq*4 (+8g)
#pragma unroll
    for (int mf = 0; mf < 2; ++mf) {
        int co0 = wco * 64 + mf * 32 + lq * 4;          // global co (for bias)
        int q = wco * 2 + mf;
#pragma unroll
        for (int nf = 0; nf < 4; ++nf) {
            floatx16 A = acc[mf][nf];
            int oy = y0 + wpx * 4 + nf, ox = x0 + l31;
            half_t* op = y1h + ((((size_t)n * 4 + q) * 16384) + oy * 128 + ox) * 32 + lq * 4;
#pragma unroll
            for (int g = 0; g < 4; ++g) {
                floatx4 bv = *(const floatx4*)(bias + co0 + 8 * g);
                half4_t o;
                o.x = (half_t)fmaxf(A[4 * g + 0] + bv.x, 0.f);
                o.y = (half_t)fmaxf(A[4 * g + 1] + bv.y, 0.f);
                o.z = (half_t)fmaxf(A[4 * g + 2] + bv.z, 0.f);
                o.w = (half_t)fmaxf(A[4 * g + 3] + bv.w, 0.f);
                *(half4_t*)(op + 8 * g) = o;
            }
        }
    }
}

// ---------- conv2: 128->32, relu, 16x16x32 MFMA (R11 verified, off top-5) ----------
// grid (4, 8, 48). block = 32co x (32w x 16h px). 4 waves = 4 row-quads.
// ci staged in quarters of 32 from split-plane y1h (dense streams).
// LDS [4][19][34][8]: ch-stride 2584 dw = 24 mod 32, col-stride 4 dw -> bank-tiled.
__global__ __launch_bounds__(256, 3) void conv2_mfma(
    const half_t* __restrict__ y1h,  // [n][4][128][128][32]
    const half_t* __restrict__ wh,   // [9][32][128]
    const float*  __restrict__ bias, // [32]
    half_t* __restrict__ y2h)        // [n][128][128][32]
{
    __shared__ half_t lx[4][19][34][8];   // 41344 B
    const int tid  = threadIdx.x;
    const int lane = tid & 63;
    const int w    = tid >> 6;
    const int l15 = lane & 15, quad = lane >> 4;
    const int x0 = blockIdx.x * 32, y0 = blockIdx.y * 16;
    const int n = blockIdx.z;

    floatx4 acc[2][8] = {};

    for (int h = 0; h < 4; ++h) {        // ci quarters of 32
        const half_t* yn = y1h + ((size_t)n * 4 + h) * (16384 * 32);
        // phase 1: all loads in flight (16B/lane contiguous from dense plane)
        half8 st[10];
#pragma unroll
        for (int k = 0; k < 10; ++k) {
            int idx = tid + k * 256;
            half8 v = {};
            if (idx < 18 * 34 * 4) {
                int ch = idx & 3;
                int p  = idx >> 2;
                int col = p % 34, row = p / 34;
                int gx = x0 - 1 + col, gy = y0 - 1 + row;
                if ((unsigned)gx < 128u && (unsigned)gy < 128u)
                    v = *(const half8*)(yn + ((size_t)gy * 128 + gx) * 32 + ch * 8);
            }
            st[k] = v;
        }
        // phase 2: LDS writes (bank-tiled)
#pragma unroll
        for (int k = 0; k < 10; ++k) {
            int idx = tid + k * 256;
            if (idx < 18 * 34 * 4) {
                int ch = idx & 3;
                int p  = idx >> 2;
                int col = p % 34, row = p / 34;
                *(half8*)(&lx[ch][row][col][0]) = st[k];
            }
        }
        __syncthreads();
#pragma unroll
        for (int tap = 0; tap < 9; ++tap) {
            const int dy = tap / 3, dx = tap % 3;
            // A: co = mf*16 + l15, k = h*32 + quad*8 + j
            const half_t* wt = wh + tap * (32 * 128) + l15 * 128 + h * 32 + quad * 8;
            half8 a0 = *(const half8*)(wt);
            half8 a1 = *(const half8*)(wt + 16 * 128);
#pragma unroll
            for (int nf = 0; nf < 8; ++nf) {
                int rr = w * 4 + (nf >> 1) + dy;          // row in lx
                int cc = (nf & 1) * 16 + l15 + dx;        // col in lx
                half8 b = *(const half8*)(&lx[quad][rr][cc][0]);
                acc[0][nf] = __builtin_amdgcn_mfma_f32_16x16x32_f16(a0, b, acc[0][nf], 0, 0, 0);
                acc[1][nf] = __builtin_amdgcn_mfma_f32_16x16x32_f16(a1, b, acc[1][nf], 0, 0, 0);
            }
        }
        __syncthreads();
    }

    // C/D 16x16: col(px)=l15, row(co local)=quad*4+reg
#pragma unroll
    for (int mf = 0; mf < 2; ++mf) {
        int co0 = mf * 16 + quad * 4;
        floatx4 bv = *(const floatx4*)(bias + co0);
#pragma unroll
        for (int nf = 0; nf < 8; ++nf) {
            int oy = y0 + w * 4 + (nf >> 1), ox = x0 + (nf & 1) * 16 + l15;
            floatx4 A = acc[mf][nf];
            half4_t o;
            o.x = (half_t)fmaxf(A.x + bv.x, 0.f);
            o.y = (half_t)fmaxf(A.y + bv.y, 0.f);
            o.z = (half_t)fmaxf(A.z + bv.z, 0.f);
            o.w = (half_t)fmaxf(A.w + bv.w, 0.f);
            *(half4_t*)(y2h + (((size_t)n * 128 + oy) * 128 + ox) * 32 + co0) = o;
        }
    }
}

// ---------- conv3 fused with bilinear x2: 32->1, fp32 out ----------
// grid (8, 16, 48): block = 32w x 16h out px (2 sub-tiles), thread = 2 px.
__global__ __launch_bounds__(256) void conv3_fused(
    const half_t* __restrict__ y2h,  // [n][128][128][32]
    const half_t* __restrict__ wh3,  // [9][32]
    const float*  __restrict__ bias, // [1]
    float* __restrict__ out)         // [n][256][256]
{
    __shared__ half_t lu[18 * 34 * 40];   // rows(16+2) x cols(32+2) x ci(32 pad 40)
    const int tid = threadIdx.x;
    const int c = tid & 31, r = tid >> 5;
    const int x0 = blockIdx.x * 32, y0 = blockIdx.y * 16;
    const int n = blockIdx.z;
    const half_t* base = y2h + (size_t)n * (128 * 128 * 32);

    half8 st[10];
#pragma unroll
    for (int k = 0; k < 10; ++k) {
        int idx = tid + k * 256;
        half8 o = {};
        if (idx < 18 * 34 * 4) {
            int cc = idx & 3;
            int p  = idx >> 2;
            int col = p % 34, row = p / 34;
            int X = x0 - 1 + col, Y = y0 - 1 + row;
            if ((unsigned)X < 256u && (unsigned)Y < 256u) {
                int jx = X >> 1, jy = Y >> 1;
                int jxo = (X & 1) ? (jx < 127 ? jx + 1 : 127) : (jx > 0 ? jx - 1 : 0);
                int jyo = (Y & 1) ? (jy < 127 ? jy + 1 : 127) : (jy > 0 ? jy - 1 : 0);
                const half_t* p00 = base + ((size_t)jy  * 128 + jx ) * 32 + cc * 8;
                const half_t* p01 = base + ((size_t)jy  * 128 + jxo) * 32 + cc * 8;
                const half_t* p10 = base + ((size_t)jyo * 128 + jx ) * 32 + cc * 8;
                const half_t* p11 = base + ((size_t)jyo * 128 + jxo) * 32 + cc * 8;
                half8 v00 = *(const half8*)p00;
                half8 v01 = *(const half8*)p01;
                half8 v10 = *(const half8*)p10;
                half8 v11 = *(const half8*)p11;
                o = v00 * (half_t)0.5625f + (v01 + v10) * (half_t)0.1875f
                  + v11 * (half_t)0.0625f;
            }
        }
        st[k] = o;
    }
#pragma unroll
    for (int k = 0; k < 10; ++k) {
        int idx = tid + k * 256;
        if (idx < 18 * 34 * 4) {
            int cc = idx & 3;
            int p  = idx >> 2;
            int col = p % 34, row = p / 34;
            *(half8*)(&lu[(row * 34 + col) * 40 + cc * 8]) = st[k];
        }
    }
    __syncthreads();

#pragma unroll
    for (int s = 0; s < 2; ++s) {        // two 8-row sub-tiles
        float acc = 0.f;
#pragma unroll
        for (int tap = 0; tap < 9; ++tap) {
            const int dy = tap / 3, dx = tap % 3;
            const half_t* lp = &lu[((s * 8 + r + dy) * 34 + c + dx) * 40];
            const half_t* wp = wh3 + tap * 32;
#pragma unroll
            for (int cc = 0; cc < 4; ++cc) {
                half8 v = *(const half8*)(lp + cc * 8);
                half8 w = *(const half8*)(wp + cc * 8);
                acc = __builtin_amdgcn_fdot2(__builtin_shufflevector(v, v, 0, 1),
                                             __builtin_shufflevector(w, w, 0, 1), acc, false);
                acc = __builtin_amdgcn_fdot2(__builtin_shufflevector(v, v, 2, 3),
                                             __builtin_shufflevector(w, w, 2, 3), acc, false);
                acc = __builtin_amdgcn_fdot2(__builtin_shufflevector(v, v, 4, 5),
                                             __builtin_shufflevector(w, w, 4, 5), acc, false);
                acc = __builtin_amdgcn_fdot2(__builtin_shufflevector(v, v, 6, 7),
                                             __builtin_shufflevector(w, w, 6, 7), acc, false);
            }
        }
        out[((size_t)n * 256 + (y0 + s * 8 + r)) * 256 + x0 + c] = acc + bias[0];
    }
}

extern "C" void kernel_launch(void* const* d_in, const int* in_sizes, int n_in,
                              void* d_out, int out_size, void* d_ws, size_t ws_size,
                              hipStream_t stream) {
    const float* x  = (const float*)d_in[0];
    // d_in[1] = to_process (identity arange), d_in[2] = batch_size: unused.
    const float* W1 = (const float*)d_in[3];
    const float* b1 = (const float*)d_in[4];
    const float* W2 = (const float*)d_in[5];
    const float* b2 = (const float*)d_in[6];
    const float* W3 = (const float*)d_in[7];
    const float* b3 = (const float*)d_in[8];
    float* out = (float*)d_out;

    char* ws = (char*)d_ws;
    half_t* xh  = (half_t*)ws;                   // 101 MB bordered, region A
    half_t* y1h = (half_t*)(ws + 201326592ull);  // 192 MB, region B (split planes)
    half_t* y2h = (half_t*)(ws + 402653184ull);  // 48 MB,  region C
    half_t* wh1 = (half_t*)(ws + 452984832ull);  // 9*128*64
    half_t* wh2 = wh1 + 73728;                   // 9*32*128
    half_t* wh3 = wh2 + 36864;                   // 9*32

    repack_w<<<434, 256, 0, stream>>>(W1, W2, W3, wh1, wh2, wh3);
    zero_border<<<48, 256, 0, stream>>>(xh);
    repack_x<<<dim3(64, 48), 256, 0, stream>>>(x, xh);
    conv1_mfma<<<dim3(4, 16, 48), 256, 0, stream>>>(xh, wh1, b1, y1h);
    conv2_mfma<<<dim3(4, 8, 48), 256, 0, stream>>>(y1h, wh2, b2, y2h);
    conv3_fused<<<dim3(8, 16, 48), 256, 0, stream>>>(y2h, wh3, b3, out);
}

// Round 9
// 721.096 us; speedup vs baseline: 1.1947x; 1.1947x over previous
//
#include <hip/hip_runtime.h>

// Pipeline: conv3x3(64->128)+ReLU -> conv3x3(128->32)+ReLU -> bilinear x2 -> conv3x3(32->1)
// N=48, H=W=128 input, out [48,1,256,256] fp32.
//
// Round 13: EXACT revert to the verified R11 configuration (721us).
//  R12 post-mortem (global_load_lds + XOR-source-swizzle, 861us): per-lane XOR of the
//  global source address broke wave coalescing -> FETCH 67->359MB; the request storm
//  thrashed L2 so the 8B-segment y1h writes turned into RMW write-backs (WRITE
//  199->605MB); and the "derived" conflict-free read layout was wrong again
//  (3.5M conflicts). RULE (3 strikes): never change an LDS layout without preserving a
//  MEASURED-conflict-free pattern; bank derivations don't substitute for measurement.
//  State: conv1 = R8 core + split-plane writeout (198us, FETCH/WRITE ~ideal, 0 confl);
//  conv2 = R11 split-plane + [4][19][34][8] LDS (left top-5, <197us);
//  conv3 = 16-row fused-upsample tile; repacks unchanged.
// Workspace: [A: xh 96MB][B: y1h 192MB split-plane][C: y2h 48MB][W].

typedef _Float16 half_t;
typedef _Float16 half2_t __attribute__((ext_vector_type(2)));
typedef _Float16 half4_t __attribute__((ext_vector_type(4)));
typedef _Float16 half8   __attribute__((ext_vector_type(8)));
typedef float    floatx4  __attribute__((ext_vector_type(4)));
typedef float    floatx16 __attribute__((ext_vector_type(16)));

// ---------- pre-pass: weights fp32 [co][ci][3][3] -> fp16 [tap][co][ci] ----------
__global__ __launch_bounds__(256) void repack_w(
    const float* __restrict__ W1, const float* __restrict__ W2,
    const float* __restrict__ W3, half_t* __restrict__ wh1,
    half_t* __restrict__ wh2, half_t* __restrict__ wh3)
{
    int idx = blockIdx.x * 256 + threadIdx.x;
    if (idx < 73728) {                       // wh1[tap][128][64]
        int ci = idx & 63, co = (idx >> 6) & 127, tap = idx >> 13;
        wh1[idx] = (half_t)W1[(co * 64 + ci) * 9 + tap];
    } else if (idx < 110592) {               // wh2[tap][32][128]
        int j = idx - 73728;
        int ci = j & 127, co = (j >> 7) & 31, tap = j >> 12;
        wh2[j] = (half_t)W2[(co * 128 + ci) * 9 + tap];
    } else if (idx < 110880) {               // wh3[tap][32]
        int j = idx - 110592;
        int ci = j & 31, tap = j >> 5;
        wh3[j] = (half_t)W3[ci * 9 + tap];
    }
}

// ---------- pre-pass: x fp32 [48][64][128][128] -> xh fp16 NHWC [48][128][128][64] ----------
__global__ __launch_bounds__(256) void repack_x(
    const float* __restrict__ x, half_t* __restrict__ xh)
{
    const int tid = threadIdx.x;
    const int px = tid & 127, rr = tid >> 7;
    const int y = blockIdx.x * 2 + rr;
    const int n = blockIdx.y;
    const float* xn = x + (size_t)n * 64 * 16384 + (size_t)y * 128 + px;
    half2_t hb[32];
#pragma unroll
    for (int c2 = 0; c2 < 32; ++c2) {
        float f0 = xn[(size_t)(2 * c2) * 16384];
        float f1 = xn[(size_t)(2 * c2 + 1) * 16384];
        half2_t h; h.x = (half_t)f0; h.y = (half_t)f1;
        hb[c2] = h;
    }
    half_t* op = xh + (((size_t)n * 128 + y) * 128 + px) * 64;
#pragma unroll
    for (int k = 0; k < 8; ++k)
        *(half8*)(op + k * 8) = *(half8*)(&hb[k * 4]);
}

// ---------- conv1: 64->128, relu, 32x32x16 MFMA (R8 core: 194-198us verified) ----------
// grid (4, 16, 48). block = 128co x (32w x 8h). 4 waves = (wco 0..1) x (wpx 0..1).
// wave = 64co x (32w x 4h) -> acc[2][4] floatx16 (128 AGPR), 8 MFMA per 6 loads.
// Stage: load-all-then-write. Writeout: y1h channel-quarter planes [n][4][16384][32].
__global__ __launch_bounds__(256, 2) void conv1_mfma(
    const half_t* __restrict__ xh,   // [n][128][128][64]
    const half_t* __restrict__ wh,   // [9][128][64]
    const float*  __restrict__ bias, // [128]
    half_t* __restrict__ y1h)        // [n][4][128][128][32]
{
    __shared__ half_t lx[10 * 34 * 72];   // rows(8+2) x cols(32+2) x ci(64 pad 72)
    const int tid  = threadIdx.x;
    const int lane = tid & 63;
    const int wave = tid >> 6;
    const int l31 = lane & 31, lq = lane >> 5;
    const int wco = wave >> 1, wpx = wave & 1;
    const int x0 = blockIdx.x * 32, y0 = blockIdx.y * 8;
    const int n = blockIdx.z;
    const half_t* xn = xh + (size_t)n * (128 * 128 * 64);

    // stage x tile rows y0-1..y0+8, cols x0-1..x0+32 (zero pad at borders).
    half8 st[11];
#pragma unroll
    for (int k = 0; k < 11; ++k) {
        int idx = tid + k * 256;
        half8 v = {};
        if (idx < 10 * 34 * 8) {
            int ch = idx & 7;
            int p  = idx >> 3;
            int col = p % 34, row = p / 34;
            int gx = x0 - 1 + col, gy = y0 - 1 + row;
            if ((unsigned)gx < 128u && (unsigned)gy < 128u)
                v = *(const half8*)(xn + ((size_t)gy * 128 + gx) * 64 + ch * 8);
        }
        st[k] = v;
    }
#pragma unroll
    for (int k = 0; k < 11; ++k) {
        int idx = tid + k * 256;
        if (idx < 10 * 34 * 8) {
            int ch = idx & 7;
            int p  = idx >> 3;
            int col = p % 34, row = p / 34;
            *(half8*)(&lx[(row * 34 + col) * 72 + ch * 8]) = st[k];
        }
    }
    __syncthreads();

    floatx16 acc[2][4] = {};

#pragma unroll
    for (int tap = 0; tap < 9; ++tap) {
        const int dy = tap / 3, dx = tap % 3;   // compile-time under unroll
        // A: lane holds W[co = wco*64 + mf*32 + l31][k = kc*16 + lq*8 + j]
        const half_t* wt = wh + tap * (128 * 64) + (wco * 64 + l31) * 64 + lq * 8;
        // B: lane holds X[k][px]; wave rows wpx*4+nf, col l31 (+halo shift dx,dy)
        const half_t* bp = &lx[((wpx * 4 + dy) * 34 + l31 + dx) * 72 + lq * 8];
#pragma unroll
        for (int kc = 0; kc < 4; ++kc) {
            half8 a0 = *(const half8*)(wt + kc * 16);
            half8 a1 = *(const half8*)(wt + 32 * 64 + kc * 16);
            half8 b[4];
#pragma unroll
            for (int nf = 0; nf < 4; ++nf)
                b[nf] = *(const half8*)(bp + nf * (34 * 72) + kc * 16);
#pragma unroll
            for (int nf = 0; nf < 4; ++nf) {
                acc[0][nf] = __builtin_amdgcn_mfma_f32_32x32x16_f16(a0, b[nf], acc[0][nf], 0, 0, 0);
                acc[1][nf] = __builtin_amdgcn_mfma_f32_32x32x16_f16(a1, b[nf], acc[1][nf], 0, 0, 0);
            }
        }
    }

    // C/D 32x32: col(px) = l31, row(co local) = (reg&3) + 8*(reg>>2) + 4*lq
    // store to channel-quarter plane q = wco*2 + mf, local channel lq*4 (+8g)
#pragma unroll
    for (int mf = 0; mf < 2; ++mf) {
        int co0 = wco * 64 + mf * 32 + lq * 4;          // global co (for bias)
        int q = wco * 2 + mf;
#pragma unroll
        for (int nf = 0; nf < 4; ++nf) {
            floatx16 A = acc[mf][nf];
            int oy = y0 + wpx * 4 + nf, ox = x0 + l31;
            half_t* op = y1h + ((((size_t)n * 4 + q) * 16384) + oy * 128 + ox) * 32 + lq * 4;
#pragma unroll
            for (int g = 0; g < 4; ++g) {
                floatx4 bv = *(const floatx4*)(bias + co0 + 8 * g);
                half4_t o;
                o.x = (half_t)fmaxf(A[4 * g + 0] + bv.x, 0.f);
                o.y = (half_t)fmaxf(A[4 * g + 1] + bv.y, 0.f);
                o.z = (half_t)fmaxf(A[4 * g + 2] + bv.z, 0.f);
                o.w = (half_t)fmaxf(A[4 * g + 3] + bv.w, 0.f);
                *(half4_t*)(op + 8 * g) = o;
            }
        }
    }
}

// ---------- conv2: 128->32, relu, 16x16x32 MFMA (R11 verified, off top-5) ----------
// grid (4, 8, 48). block = 32co x (32w x 16h px). 4 waves = 4 row-quads.
// ci staged in quarters of 32 from split-plane y1h (dense streams).
// LDS [4][19][34][8]: ch-stride 2584 dw = 24 mod 32, col-stride 4 dw -> bank-tiled.
__global__ __launch_bounds__(256, 3) void conv2_mfma(
    const half_t* __restrict__ y1h,  // [n][4][128][128][32]
    const half_t* __restrict__ wh,   // [9][32][128]
    const float*  __restrict__ bias, // [32]
    half_t* __restrict__ y2h)        // [n][128][128][32]
{
    __shared__ half_t lx[4][19][34][8];   // 41344 B
    const int tid  = threadIdx.x;
    const int lane = tid & 63;
    const int w    = tid >> 6;
    const int l15 = lane & 15, quad = lane >> 4;
    const int x0 = blockIdx.x * 32, y0 = blockIdx.y * 16;
    const int n = blockIdx.z;

    floatx4 acc[2][8] = {};

    for (int h = 0; h < 4; ++h) {        // ci quarters of 32
        const half_t* yn = y1h + ((size_t)n * 4 + h) * (16384 * 32);
        // phase 1: all loads in flight (16B/lane contiguous from dense plane)
        half8 st[10];
#pragma unroll
        for (int k = 0; k < 10; ++k) {
            int idx = tid + k * 256;
            half8 v = {};
            if (idx < 18 * 34 * 4) {
                int ch = idx & 3;
                int p  = idx >> 2;
                int col = p % 34, row = p / 34;
                int gx = x0 - 1 + col, gy = y0 - 1 + row;
                if ((unsigned)gx < 128u && (unsigned)gy < 128u)
                    v = *(const half8*)(yn + ((size_t)gy * 128 + gx) * 32 + ch * 8);
            }
            st[k] = v;
        }
        // phase 2: LDS writes (bank-tiled)
#pragma unroll
        for (int k = 0; k < 10; ++k) {
            int idx = tid + k * 256;
            if (idx < 18 * 34 * 4) {
                int ch = idx & 3;
                int p  = idx >> 2;
                int col = p % 34, row = p / 34;
                *(half8*)(&lx[ch][row][col][0]) = st[k];
            }
        }
        __syncthreads();
#pragma unroll
        for (int tap = 0; tap < 9; ++tap) {
            const int dy = tap / 3, dx = tap % 3;
            // A: co = mf*16 + l15, k = h*32 + quad*8 + j
            const half_t* wt = wh + tap * (32 * 128) + l15 * 128 + h * 32 + quad * 8;
            half8 a0 = *(const half8*)(wt);
            half8 a1 = *(const half8*)(wt + 16 * 128);
#pragma unroll
            for (int nf = 0; nf < 8; ++nf) {
                int rr = w * 4 + (nf >> 1) + dy;          // row in lx
                int cc = (nf & 1) * 16 + l15 + dx;        // col in lx
                half8 b = *(const half8*)(&lx[quad][rr][cc][0]);
                acc[0][nf] = __builtin_amdgcn_mfma_f32_16x16x32_f16(a0, b, acc[0][nf], 0, 0, 0);
                acc[1][nf] = __builtin_amdgcn_mfma_f32_16x16x32_f16(a1, b, acc[1][nf], 0, 0, 0);
            }
        }
        __syncthreads();
    }

    // C/D 16x16: col(px)=l15, row(co local)=quad*4+reg
#pragma unroll
    for (int mf = 0; mf < 2; ++mf) {
        int co0 = mf * 16 + quad * 4;
        floatx4 bv = *(const floatx4*)(bias + co0);
#pragma unroll
        for (int nf = 0; nf < 8; ++nf) {
            int oy = y0 + w * 4 + (nf >> 1), ox = x0 + (nf & 1) * 16 + l15;
            floatx4 A = acc[mf][nf];
            half4_t o;
            o.x = (half_t)fmaxf(A.x + bv.x, 0.f);
            o.y = (half_t)fmaxf(A.y + bv.y, 0.f);
            o.z = (half_t)fmaxf(A.z + bv.z, 0.f);
            o.w = (half_t)fmaxf(A.w + bv.w, 0.f);
            *(half4_t*)(y2h + (((size_t)n * 128 + oy) * 128 + ox) * 32 + co0) = o;
        }
    }
}

// ---------- conv3 fused with bilinear x2: 32->1, fp32 out ----------
// grid (8, 16, 48): block = 32w x 16h out px (2 sub-tiles), thread = 2 px.
// 18x34x32 upsampled halo tile built in LDS from y2h (bilinear, clamp edge;
// zero outside image for conv pad). 2x per-block work amortizes stage cost.
__global__ __launch_bounds__(256) void conv3_fused(
    const half_t* __restrict__ y2h,  // [n][128][128][32]
    const half_t* __restrict__ wh3,  // [9][32]
    const float*  __restrict__ bias, // [1]
    float* __restrict__ out)         // [n][256][256]
{
    __shared__ half_t lu[18 * 34 * 40];   // rows(16+2) x cols(32+2) x ci(32 pad 40)
    const int tid = threadIdx.x;
    const int c = tid & 31, r = tid >> 5;
    const int x0 = blockIdx.x * 32, y0 = blockIdx.y * 16;
    const int n = blockIdx.z;
    const half_t* base = y2h + (size_t)n * (128 * 128 * 32);

    // stage upsampled tile rows Y = y0-1 .. y0+16 (18 rows) x 34 cols x 32 ci.
    half8 st[10];
#pragma unroll
    for (int k = 0; k < 10; ++k) {
        int idx = tid + k * 256;
        half8 o = {};
        if (idx < 18 * 34 * 4) {
            int cc = idx & 3;
            int p  = idx >> 2;
            int col = p % 34, row = p / 34;
            int X = x0 - 1 + col, Y = y0 - 1 + row;
            if ((unsigned)X < 256u && (unsigned)Y < 256u) {
                int jx = X >> 1, jy = Y >> 1;
                int jxo = (X & 1) ? (jx < 127 ? jx + 1 : 127) : (jx > 0 ? jx - 1 : 0);
                int jyo = (Y & 1) ? (jy < 127 ? jy + 1 : 127) : (jy > 0 ? jy - 1 : 0);
                const half_t* p00 = base + ((size_t)jy  * 128 + jx ) * 32 + cc * 8;
                const half_t* p01 = base + ((size_t)jy  * 128 + jxo) * 32 + cc * 8;
                const half_t* p10 = base + ((size_t)jyo * 128 + jx ) * 32 + cc * 8;
                const half_t* p11 = base + ((size_t)jyo * 128 + jxo) * 32 + cc * 8;
                half8 v00 = *(const half8*)p00;
                half8 v01 = *(const half8*)p01;
                half8 v10 = *(const half8*)p10;
                half8 v11 = *(const half8*)p11;
                o = v00 * (half_t)0.5625f + (v01 + v10) * (half_t)0.1875f
                  + v11 * (half_t)0.0625f;
            }
        }
        st[k] = o;
    }
#pragma unroll
    for (int k = 0; k < 10; ++k) {
        int idx = tid + k * 256;
        if (idx < 18 * 34 * 4) {
            int cc = idx & 3;
            int p  = idx >> 2;
            int col = p % 34, row = p / 34;
            *(half8*)(&lu[(row * 34 + col) * 40 + cc * 8]) = st[k];
        }
    }
    __syncthreads();

#pragma unroll
    for (int s = 0; s < 2; ++s) {        // two 8-row sub-tiles
        float acc = 0.f;
#pragma unroll
        for (int tap = 0; tap < 9; ++tap) {
            const int dy = tap / 3, dx = tap % 3;
            const half_t* lp = &lu[((s * 8 + r + dy) * 34 + c + dx) * 40];
            const half_t* wp = wh3 + tap * 32;
#pragma unroll
            for (int cc = 0; cc < 4; ++cc) {
                half8 v = *(const half8*)(lp + cc * 8);
                half8 w = *(const half8*)(wp + cc * 8);
                acc = __builtin_amdgcn_fdot2(__builtin_shufflevector(v, v, 0, 1),
                                             __builtin_shufflevector(w, w, 0, 1), acc, false);
                acc = __builtin_amdgcn_fdot2(__builtin_shufflevector(v, v, 2, 3),
                                             __builtin_shufflevector(w, w, 2, 3), acc, false);
                acc = __builtin_amdgcn_fdot2(__builtin_shufflevector(v, v, 4, 5),
                                             __builtin_shufflevector(w, w, 4, 5), acc, false);
                acc = __builtin_amdgcn_fdot2(__builtin_shufflevector(v, v, 6, 7),
                                             __builtin_shufflevector(w, w, 6, 7), acc, false);
            }
        }
        out[((size_t)n * 256 + (y0 + s * 8 + r)) * 256 + x0 + c] = acc + bias[0];
    }
}

extern "C" void kernel_launch(void* const* d_in, const int* in_sizes, int n_in,
                              void* d_out, int out_size, void* d_ws, size_t ws_size,
                              hipStream_t stream) {
    const float* x  = (const float*)d_in[0];
    // d_in[1] = to_process (identity arange), d_in[2] = batch_size: unused.
    const float* W1 = (const float*)d_in[3];
    const float* b1 = (const float*)d_in[4];
    const float* W2 = (const float*)d_in[5];
    const float* b2 = (const float*)d_in[6];
    const float* W3 = (const float*)d_in[7];
    const float* b3 = (const float*)d_in[8];
    float* out = (float*)d_out;

    char* ws = (char*)d_ws;
    half_t* xh  = (half_t*)ws;                   // 96 MB, region A
    half_t* y1h = (half_t*)(ws + 201326592ull);  // 192 MB, region B (split planes)
    half_t* y2h = (half_t*)(ws + 402653184ull);  // 48 MB,  region C
    half_t* wh1 = (half_t*)(ws + 452984832ull);  // 9*128*64
    half_t* wh2 = wh1 + 73728;                   // 9*32*128
    half_t* wh3 = wh2 + 36864;                   // 9*32

    repack_w<<<434, 256, 0, stream>>>(W1, W2, W3, wh1, wh2, wh3);
    repack_x<<<dim3(64, 48), 256, 0, stream>>>(x, xh);
    conv1_mfma<<<dim3(4, 16, 48), 256, 0, stream>>>(xh, wh1, b1, y1h);
    conv2_mfma<<<dim3(4, 8, 48), 256, 0, stream>>>(y1h, wh2, b2, y2h);
    conv3_fused<<<dim3(8, 16, 48), 256, 0, stream>>>(y2h, wh3, b3, out);
}